// Round 1
// 264.413 us; speedup vs baseline: 1.0040x; 1.0040x over previous
//
#include <hip/hip_runtime.h>
#include <hip/hip_bf16.h>
#include <stdint.h>

// Problem constants
#define BATCH 4
#define SEQ   4096
#define HID   1024
#define NH    16
#define HD    64
#define CS    16
#define NCH   256          // SEQ/CS
#define MROWS 16384        // BATCH*SEQ

typedef __attribute__((ext_vector_type(8))) __bf16 bf16x8;
typedef __attribute__((ext_vector_type(4))) float  f32x4;

__device__ __forceinline__ unsigned short f2bf(float f) {
    union { float f; unsigned u; } x; x.f = f;
    unsigned r = x.u + 0x7FFFu + ((x.u >> 16) & 1u);   // RNE
    return (unsigned short)(r >> 16);
}
__device__ __forceinline__ float bf2f(unsigned short v) {
    union { unsigned u; float f; } x; x.u = ((unsigned)v) << 16;
    return x.f;
}

__device__ __forceinline__ void async_copy16(void* lds, const void* g) {
    __builtin_amdgcn_global_load_lds(
        (const __attribute__((address_space(1))) unsigned int*)g,
        (__attribute__((address_space(3))) unsigned int*)lds,
        16, 0, 0);
}

#define FENCE() asm volatile("" ::: "memory")
#define BARRIER() do { FENCE(); __builtin_amdgcn_s_barrier(); FENCE(); } while (0)

// ---------------------------------------------------------------- convert (all inputs, one kernel)
__global__ __launch_bounds__(256) void convert_all_kernel(
    const float* __restrict__ x, const float* __restrict__ W_in,
    const float* __restrict__ W_out, const float* __restrict__ W_gate,
    unsigned short* __restrict__ xb, unsigned short* __restrict__ Wib,
    unsigned short* __restrict__ Wob, unsigned short* __restrict__ Wgb)
{
    int i = blockIdx.x * 256 + threadIdx.x;
    const float4* src; ushort4* dst; int j;
    if (i < 4194304)      { src = (const float4*)x;      dst = (ushort4*)xb;  j = i; }
    else if (i < 4456448) { src = (const float4*)W_in;   dst = (ushort4*)Wib; j = i - 4194304; }
    else if (i < 4718592) { src = (const float4*)W_out;  dst = (ushort4*)Wob; j = i - 4456448; }
    else if (i < 4726784) { src = (const float4*)W_gate; dst = (ushort4*)Wgb; j = i - 4718592; }
    else return;
    float4 v = src[j];
    ushort4 o;
    o.x = f2bf(v.x); o.y = f2bf(v.y); o.z = f2bf(v.z); o.w = f2bf(v.w);
    dst[j] = o;
}

// ---------------------------------------------------------------- GEMM (C = A @ B^T), bf16 in, fp32 out
// 256x256 tile, BK=64, 8 waves (2Mx4N), double-buffered 128KB LDS,
// 4-phase deep-pipelined schedule: counted vmcnt (never drains to 0 in
// main loop), raw s_barrier, setprio around MFMA clusters, XOR-swizzled
// LDS via pre-swizzled global source (same scheme as verified 128² kernel).
#define GBM 256
#define GBN 256
#define GBK 64

__global__ __launch_bounds__(512, 2) void gemm256_kernel(
    const unsigned short* __restrict__ A,
    const unsigned short* __restrict__ Bm,
    float* __restrict__ C, int M, int N, int K)
{
    __shared__ unsigned short As[2][GBM][GBK];   // 64 KB
    __shared__ unsigned short Bs[2][GBN][GBK];   // 64 KB

    const int t = threadIdx.x;
    const int lane = t & 63, w = t >> 6;
    const int wm = w >> 2, wn = w & 3;           // wave grid 2(M) x 4(N)

    // bijective XCD swizzle (gridDim.x % 8 == 0 here: 256 blocks)
    const int nwg = gridDim.x;
    const int cpx = nwg >> 3;
    const int bid = blockIdx.x;
    const int swz = (bid & 7) * cpx + (bid >> 3);
    const int ntile = N >> 8;                    // N/256
    const size_t bm = (size_t)(swz / ntile) * GBM;
    const size_t bn = (size_t)(swz % ntile) * GBN;

    // ---- staging map: thread t covers chunks {t, t+512} of each 128x64 half
    // physical chunk sp of row r holds logical chunk sp ^ (r&7) (pre-swizzled source)
    const int srow = t >> 3;                     // 0..63 (and +64 for 2nd load)
    const int sp   = t & 7;
    const int sgc  = sp ^ (srow & 7);            // (srow+64)&7 == srow&7, same gc
    const unsigned short* Ag = A  + (bm + srow) * (size_t)K + sgc * 8;
    const unsigned short* Bg = Bm + (bn + srow) * (size_t)K + sgc * 8;

    const int fr = lane & 15, fq = lane >> 4;
    const int frl = fr & 7;

    f32x4 acc[8][4];
#pragma unroll
    for (int x = 0; x < 8; x++)
#pragma unroll
        for (int y = 0; y < 4; y++)
            acc[x][y] = (f32x4){0.f, 0.f, 0.f, 0.f};

    bf16x8 afr[4][2];          // current A x-half fragments (rows xh*64 + x*16)
    bf16x8 bf0[2][2];          // B cols wn*64 + {0..31}
    bf16x8 bf1[2][2];          // B cols wn*64 + {32..63}

    // stage half h (0,1 = A halves; 2,3 = B halves) of K-tile at k0 into buffer par
    auto stage = [&](int par, int h, int k0) {
        if (h < 2) {
            const unsigned short* g = Ag + ((size_t)h * 128) * K + k0;
            unsigned short* l = &As[par][h * 128 + srow][sp * 8];
            async_copy16(l,            g);
            async_copy16(l + 64 * GBK, g + (size_t)64 * K);
        } else {
            const int hh = h - 2;
            const unsigned short* g = Bg + ((size_t)hh * 128) * K + k0;
            unsigned short* l = &Bs[par][hh * 128 + srow][sp * 8];
            async_copy16(l,            g);
            async_copy16(l + 64 * GBK, g + (size_t)64 * K);
        }
    };
    auto rdA = [&](int par, int xh) {
#pragma unroll
        for (int x = 0; x < 4; x++)
#pragma unroll
            for (int kk = 0; kk < 2; kk++)
                afr[x][kk] = *(const bf16x8*)&As[par][wm * 128 + xh * 64 + x * 16 + fr]
                                                    [((kk * 4 + fq) ^ frl) * 8];
    };
    auto rdB = [&](int par, int yh, bf16x8 (&bfv)[2][2]) {
#pragma unroll
        for (int y = 0; y < 2; y++)
#pragma unroll
            for (int kk = 0; kk < 2; kk++)
                bfv[y][kk] = *(const bf16x8*)&Bs[par][wn * 64 + yh * 32 + y * 16 + fr]
                                                    [((kk * 4 + fq) ^ frl) * 8];
    };
    auto mm = [&](bf16x8 (&bfv)[2][2], int x0, int y0) {
        __builtin_amdgcn_s_setprio(1);
#pragma unroll
        for (int kk = 0; kk < 2; kk++)
#pragma unroll
            for (int x = 0; x < 4; x++)
#pragma unroll
                for (int y = 0; y < 2; y++)
                    acc[x0 + x][y0 + y] = __builtin_amdgcn_mfma_f32_16x16x32_bf16(
                        afr[x][kk], bfv[y][kk], acc[x0 + x][y0 + y], 0, 0, 0);
        __builtin_amdgcn_s_setprio(0);
    };

    const int NT = K >> 6;

    // ---- prologue: stage tile 0 into buf0 (only vmcnt(0) of the whole kernel body)
#pragma unroll
    for (int h = 0; h < 4; h++) stage(0, h, 0);
    asm volatile("s_waitcnt vmcnt(0)" ::: "memory");
    BARRIER();

    int par = 0;
    for (int tt = 0; tt < NT - 1; ++tt, par ^= 1) {
        const int k1 = (tt + 1) << 6;
        // phase 0: issue next-tile half0 FIRST, then counted wait (2 newest stay in flight)
        stage(par ^ 1, 0, k1);
        asm volatile("s_waitcnt vmcnt(2)" ::: "memory");
        BARRIER();
        rdA(par, 0); rdB(par, 0, bf0);
        mm(bf0, 0, 0);
        BARRIER();
        // phase 1
        rdB(par, 1, bf1);
        stage(par ^ 1, 1, k1);
        BARRIER();
        mm(bf1, 0, 2);
        BARRIER();
        // phase 2
        rdA(par, 1);
        stage(par ^ 1, 2, k1);
        BARRIER();
        mm(bf0, 4, 0);
        BARRIER();
        // phase 3 (no new ds_reads: all fragments register-resident)
        stage(par ^ 1, 3, k1);
        BARRIER();
        mm(bf1, 4, 2);
        BARRIER();
    }

    // ---- epilogue: last tile, no staging
    asm volatile("s_waitcnt vmcnt(0)" ::: "memory");
    BARRIER();
    rdA(par, 0); rdB(par, 0, bf0);
    mm(bf0, 0, 0);
    rdB(par, 1, bf1);
    mm(bf1, 0, 2);
    rdA(par, 1);
    mm(bf0, 4, 0);
    mm(bf1, 4, 2);

    // ---- C write (fp32), same fragment->C mapping as verified 128² kernel
#pragma unroll
    for (int x = 0; x < 8; x++) {
#pragma unroll
        for (int y = 0; y < 4; y++) {
            const size_t r0 = bm + wm * 128 + x * 16 + fq * 4;
            const size_t c  = bn + wn * 64 + y * 16 + fr;
#pragma unroll
            for (int rg = 0; rg < 4; rg++)
                C[(r0 + rg) * (size_t)N + c] = acc[x][y][rg];
        }
    }
}

// ---------------------------------------------------------------- mid: LN + MFMA gates + scan1 (prefix form)
__global__ __launch_bounds__(256) void mid_kernel(
    const float* __restrict__ xp,
    const float* __restrict__ ln_g, const float* __restrict__ ln_b,
    const unsigned short* __restrict__ Wgb,   // bf16 [32][1024]
    const float* __restrict__ bg, const float* __restrict__ eig_raw,
    unsigned short* __restrict__ xln,         // out: [MROWS][1024] bf16
    float* __restrict__ beta_buf,             // out: [MROWS][16]
    float* __restrict__ cum_out,              // out: [1024][16][16]
    float* __restrict__ c15c,                 // out: [1024][16]
    float* __restrict__ hc15)                 // out: [1024][1024]
{
    __shared__ unsigned short sx[16][1032];   // 33KB, +8 pad
    __shared__ float red[4][2][64][4];        // 8KB partial gate accs
    __shared__ float sg[16][32];
    __shared__ float scum[16][16];
    const int t = threadIdx.x, lane = t & 63, w = t >> 6;
    const int bn = blockIdx.x;
    const size_t m0 = (size_t)(bn >> 8) * SEQ + (size_t)(bn & 255) * 16;

    // ---- LayerNorm (row r = t>>4, 64 elems per thread)
    const int r = t >> 4, u = t & 15;
    {
        const float* row = xp + (m0 + r) * 1024;
        float4 v[16];
        float s = 0.f, s2 = 0.f;
#pragma unroll
        for (int i = 0; i < 16; i++) {
            v[i] = *(const float4*)(row + u * 4 + i * 64);
            s  += v[i].x + v[i].y + v[i].z + v[i].w;
            s2 += v[i].x * v[i].x + v[i].y * v[i].y + v[i].z * v[i].z + v[i].w * v[i].w;
        }
#pragma unroll
        for (int off = 1; off < 16; off <<= 1) {
            s  += __shfl_xor(s, off, 64);
            s2 += __shfl_xor(s2, off, 64);
        }
        const float mu = s * (1.f / 1024.f);
        const float var = s2 * (1.f / 1024.f) - mu * mu;
        const float sc = rsqrtf(var + 1e-5f);
        unsigned short* orow = xln + (m0 + r) * 1024;
#pragma unroll
        for (int i = 0; i < 16; i++) {
            const int k = u * 4 + i * 64;
            float4 g4 = *(const float4*)(ln_g + k);
            float4 b4 = *(const float4*)(ln_b + k);
            ushort4 o;
            o.x = f2bf((v[i].x - mu) * sc * g4.x + b4.x);
            o.y = f2bf((v[i].y - mu) * sc * g4.y + b4.y);
            o.z = f2bf((v[i].z - mu) * sc * g4.z + b4.z);
            o.w = f2bf((v[i].w - mu) * sc * g4.w + b4.w);
            *(ushort4*)&sx[r][k] = o;
            *(ushort4*)(orow + k) = o;
        }
    }
    __syncthreads();

    // ---- gates via MFMA: wave w covers K in [w*256,(w+1)*256)
    const int fr = lane & 15, fq = lane >> 4;
    {
        f32x4 acc0 = (f32x4){0.f,0.f,0.f,0.f}, acc1 = (f32x4){0.f,0.f,0.f,0.f};
        const unsigned short* Wr0 = Wgb + (size_t)fr * 1024;
        const unsigned short* Wr1 = Wgb + (size_t)(16 + fr) * 1024;
#pragma unroll
        for (int ks = 0; ks < 8; ks++) {
            const int k0 = w * 256 + ks * 32 + fq * 8;
            bf16x8 af = *(const bf16x8*)&sx[fr][k0];
            bf16x8 b0 = *(const bf16x8*)(Wr0 + k0);
            bf16x8 b1 = *(const bf16x8*)(Wr1 + k0);
            acc0 = __builtin_amdgcn_mfma_f32_16x16x32_bf16(af, b0, acc0, 0, 0, 0);
            acc1 = __builtin_amdgcn_mfma_f32_16x16x32_bf16(af, b1, acc1, 0, 0, 0);
        }
        *(f32x4*)&red[w][0][lane][0] = acc0;
        *(f32x4*)&red[w][1][lane][0] = acc1;
    }
    __syncthreads();
    if (t < 128) {
        const int y = t >> 6, l = t & 63;
        f32x4 s = *(const f32x4*)&red[0][y][l][0];
#pragma unroll
        for (int ww = 1; ww < 4; ww++) {
            f32x4 p = *(const f32x4*)&red[ww][y][l][0];
            s[0] += p[0]; s[1] += p[1]; s[2] += p[2]; s[3] += p[3];
        }
        const int col = y * 16 + (l & 15);
        const int row0 = (l >> 4) * 4;
        const float bias = bg[col];
#pragma unroll
        for (int rg = 0; rg < 4; rg++)
            sg[row0 + rg][col] = 1.f / (1.f + expf(-(s[rg] + bias)));
    }
    __syncthreads();

    // ---- cumprod of a = tanh(eig)*alpha
    if (t < 16) {
        const float ev = tanhf(eig_raw[t]);
        float c = 1.f;
#pragma unroll
        for (int i = 0; i < 16; i++) { c *= ev * sg[i][t]; scum[i][t] = c; }
    }
    // beta out
    beta_buf[(m0 + r) * 16 + u] = sg[r][16 + u];
    __syncthreads();

    // cum/c15 out
    cum_out[(size_t)bn * 256 + t] = scum[t >> 4][t & 15];
    if (t < 16) c15c[bn * 16 + t] = scum[15][t];

    // ---- hc15 via prefix form: hc15 = cum15 * sum_{j<15} bb[j]/cpad[j] + bb[15]
    {
        const int h = t >> 4, d0 = (t & 15) * 4;
        float s0 = 0.f, s1 = 0.f, s2 = 0.f, s3 = 0.f;
        float b0 = 0.f, b1 = 0.f, b2 = 0.f, b3 = 0.f;
        float cprev = 1.f;
#pragma unroll
        for (int j = 0; j < 16; j++) {
            const float bt = sg[j][16 + h];
            ushort4 xv = *(const ushort4*)&sx[j][h * 64 + d0];
            b0 = bt * bf2f(xv.x); b1 = bt * bf2f(xv.y);
            b2 = bt * bf2f(xv.z); b3 = bt * bf2f(xv.w);
            if (j < 15) {
                const float inv = (fabsf(cprev) > 1e-8f) ? (1.f / cprev) : 0.f;
                s0 += b0 * inv; s1 += b1 * inv; s2 += b2 * inv; s3 += b3 * inv;
                cprev = scum[j][h];
            }
        }
        const float c15 = scum[15][h];
        float4 o = { c15 * s0 + b0, c15 * s1 + b1, c15 * s2 + b2, c15 * s3 + b3 };
        *(float4*)(hc15 + (size_t)bn * 1024 + h * 64 + d0) = o;
    }
}

// ---------------------------------------------------------------- scan phase 2 (sequential carry)
__global__ __launch_bounds__(64) void scan2_kernel(
    const float* __restrict__ c15c,      // [1024][16]
    const float* __restrict__ hc15,      // [1024][1024]
    float* __restrict__ carry_in,        // [1024][1024]
    float* __restrict__ h_final)         // [4][1024]
{
    const int p = blockIdx.x * 64 + threadIdx.x;   // 0..4095
    const int b = p >> 10, hd = p & 1023, h = hd >> 6;
    float carry = 0.f;
#pragma unroll 8
    for (int n = 0; n < NCH; n++) {
        const size_t bn = (size_t)b * NCH + n;
        const float c15 = c15c[bn * 16 + h];
        carry_in[bn * 1024 + hd] = carry;
        carry = c15 * carry + hc15[bn * 1024 + hd];
    }
    h_final[(size_t)b * 1024 + hd] = carry;
}

// ---------------------------------------------------------------- scan phase 3: prefix form, register-resident
// h[i] = cum[i]*(carry + sum_{j<i} bb[j]/cpad[j]) + bb[i]
__global__ __launch_bounds__(256) void scan3_kernel(
    const float* __restrict__ cum_buf,
    const float* __restrict__ beta_buf,
    const unsigned short* __restrict__ xln,
    const float* __restrict__ carry_in,
    unsigned short* __restrict__ hall)          // [MROWS][1024] bf16
{
    __shared__ float scum[16][16];
    __shared__ float sbeta[16][16];
    const int t = threadIdx.x;
    const int bn = blockIdx.x;
    const size_t m0 = (size_t)(bn >> 8) * SEQ + (size_t)(bn & 255) * 16;

    scum[t >> 4][t & 15]  = cum_buf[(size_t)bn * 256 + t];
    sbeta[t >> 4][t & 15] = beta_buf[(m0 + (t >> 4)) * 16 + (t & 15)];
    __syncthreads();

    const int h = t >> 4, dq = t & 15;
    const size_t off = h * 64 + dq * 4;
    float4 s = *(const float4*)(carry_in + (size_t)bn * 1024 + off);
    float cprev = 1.f;
#pragma unroll
    for (int i = 0; i < 16; i++) {
        ushort4 xv = *(const ushort4*)(xln + (m0 + i) * 1024 + off);
        const float bt = sbeta[i][h];
        const float b0 = bt * bf2f(xv.x), b1 = bt * bf2f(xv.y),
                    b2 = bt * bf2f(xv.z), b3 = bt * bf2f(xv.w);
        const float ci = scum[i][h];
        ushort4 o;
        o.x = f2bf(ci * s.x + b0); o.y = f2bf(ci * s.y + b1);
        o.z = f2bf(ci * s.z + b2); o.w = f2bf(ci * s.w + b3);
        *(ushort4*)(hall + (m0 + i) * 1024 + off) = o;
        const float inv = (fabsf(cprev) > 1e-8f) ? (1.f / cprev) : 0.f;
        s.x += b0 * inv; s.y += b1 * inv; s.z += b2 * inv; s.w += b3 * inv;
        cprev = ci;
    }
}

// ---------------------------------------------------------------- launch
extern "C" void kernel_launch(void* const* d_in, const int* in_sizes, int n_in,
                              void* d_out, int out_size, void* d_ws, size_t ws_size,
                              hipStream_t stream)
{
    const float* x       = (const float*)d_in[0];
    const float* W_in    = (const float*)d_in[1];
    const float* ln_g    = (const float*)d_in[2];
    const float* ln_b    = (const float*)d_in[3];
    const float* W_gate  = (const float*)d_in[4];
    const float* b_gate  = (const float*)d_in[5];
    const float* eig_raw = (const float*)d_in[6];
    const float* W_out   = (const float*)d_in[7];
    float* out = (float*)d_out;

    char* ws = (char*)d_ws;
    unsigned short* xb   = (unsigned short*)(ws);                   // 32MB; reused as xln after gemm1
    unsigned short* xln  = (unsigned short*)(ws);
    unsigned short* hall = (unsigned short*)(ws + 33554432);        // 32MB
    unsigned short* Wib  = (unsigned short*)(ws + 67108864);        // 2MB
    unsigned short* Wob  = (unsigned short*)(ws + 69206016);        // 2MB
    unsigned short* Wgb  = (unsigned short*)(ws + 71303168);        // 64KB
    float* beta_buf = (float*)(ws + 71368704);                      // 1MB
    float* cum_buf  = (float*)(ws + 72417280);                      // 1MB
    float* c15c     = (float*)(ws + 73465856);                      // 64KB
    float* hc15     = (float*)(ws + 73531392);                      // 4MB
    float* carry_in = (float*)(ws + 77725696);                      // 4MB  (end ~78.2MB)

    float* xp = out;                       // d_out head doubles as xp scratch
    float* h_final = out + 16777216;

    convert_all_kernel<<<18464, 256, 0, stream>>>(x, W_in, W_out, W_gate, xb, Wib, Wob, Wgb);

    // grid = (M/256)*(N/256) = 64*4 = 256 blocks (1 per CU), 512 threads
    gemm256_kernel<<<256, 512, 0, stream>>>(xb, Wib, xp, MROWS, HID, HID);

    mid_kernel<<<1024, 256, 0, stream>>>(xp, ln_g, ln_b, Wgb, b_gate, eig_raw,
                                         xln, beta_buf, cum_buf, c15c, hc15);

    scan2_kernel<<<64, 64, 0, stream>>>(c15c, hc15, carry_in, h_final);
    scan3_kernel<<<1024, 256, 0, stream>>>(cum_buf, beta_buf, xln, carry_in, hall);

    gemm256_kernel<<<256, 512, 0, stream>>>(hall, Wob, out, MROWS, HID, HID);
}